// Round 6
// baseline (626.062 us; speedup 1.0000x reference)
//
#include <hip/hip_runtime.h>

// profileperm VQ encode+decode. Key insight from rounds 1/5: the harness's
// ref=np recompute is FP32 numpy (BLAS sgemm + pairwise np.sum). A more-precise
// (fp64) argmin DISAGREES with it on micro-gap ties (~1e3 rows -> absmax ~1.3).
// So this kernel replicates numpy's fp32 arithmetic BIT-EXACTLY:
//   dot  = sgemm K=8: fl(x0*c0); fmaf(xk,ck,acc) ascending k   (single accumulator)
//   score= fl(-2*dot + c2) == fmaf(-2.0f, dot, c2)   (-2*dot is exact)
//   c2   = numpy pairwise tree of separately-rounded squares (n=8):
//          ((q0+q1)+(q2+q3))+((q4+q5)+(q6+q7)),  q=__fmul_rn(c,c)
//   argmin = first-min (strict <, ascending index)
// Output values are bit-exact centroid pass-throughs.

constexpr int N_ROWS = 262144;
constexpr int D   = 128;
constexpr int NB  = 16;   // blocks
constexpr int NC  = 256;  // centroids per block
constexpr int BD  = 8;    // block dim
constexpr int TPB = 1024; // 16 waves
constexpr int RPL = 4;    // rows per lane
constexpr int ROWS_PER_ITER = 64 * RPL; // 256 rows per group iteration

__global__ __launch_bounds__(TPB, 1)
void vq_np_exact(const float* __restrict__ x,
                 const float* __restrict__ cent,
                 const int*   __restrict__ perm,
                 float*       __restrict__ out) {
  extern __shared__ float lds[];
  float* cs = lds;                 // [NB][NC][BD] : centroids (plain)
  float* c2 = lds + NB * NC * BD;  // [NB][NC]    : np-pairwise sum(c*c), fp32
  const int t = threadIdx.x;

  for (int i = t; i < NB * NC * BD; i += TPB) cs[i] = cent[i];
  for (int i = t; i < NB * NC; i += TPB) {
    const float* c = cent + i * BD;
    // numpy: sq = c*c (each square rounded), np.sum pairwise tree for n=8.
    const float q0 = __fmul_rn(c[0], c[0]);
    const float q1 = __fmul_rn(c[1], c[1]);
    const float q2 = __fmul_rn(c[2], c[2]);
    const float q3 = __fmul_rn(c[3], c[3]);
    const float q4 = __fmul_rn(c[4], c[4]);
    const float q5 = __fmul_rn(c[5], c[5]);
    const float q6 = __fmul_rn(c[6], c[6]);
    const float q7 = __fmul_rn(c[7], c[7]);
    const float s01 = __fadd_rn(q0, q1);
    const float s23 = __fadd_rn(q2, q3);
    const float s45 = __fadd_rn(q4, q5);
    const float s67 = __fadd_rn(q6, q7);
    c2[i] = __fadd_rn(__fadd_rn(s01, s23), __fadd_rn(s45, s67));
  }
  __syncthreads();

  const int wave = t >> 6;
  const int lane = t & 63;
  const int b = wave;  // block index owned by this wave

  int pc[BD];  // permuted columns for this block (wave-uniform)
#pragma unroll
  for (int j = 0; j < BD; ++j) pc[j] = perm[b * BD + j];

  const float* cB  = cs + b * NC * BD;
  const float* c2B = c2 + b * NC;

  for (int n0 = blockIdx.x * ROWS_PER_ITER; n0 < N_ROWS;
       n0 += gridDim.x * ROWS_PER_ITER) {
    float xr[RPL][BD];
#pragma unroll
    for (int r = 0; r < RPL; ++r) {
      const float* xn = x + (size_t)(n0 + r * 64 + lane) * D;
#pragma unroll
      for (int j = 0; j < BD; ++j) xr[r][j] = xn[pc[j]];
    }

    float m1[RPL];
    int   i1[RPL];
#pragma unroll
    for (int r = 0; r < RPL; ++r) { m1[r] = __builtin_inff(); i1[r] = 0; }

#pragma unroll 2
    for (int c = 0; c < NC; ++c) {
      const float4 ca  = *reinterpret_cast<const float4*>(cB + c * BD);
      const float4 cb  = *reinterpret_cast<const float4*>(cB + c * BD + 4);
      const float  cc2 = c2B[c];
#pragma unroll
      for (int r = 0; r < RPL; ++r) {
        // BLAS sgemm K=8 dot: acc=0, sequential FMA ascending k.
        float d = __fmul_rn(xr[r][0], ca.x);   // fl(x0*c0) == fma(x0,c0,0)
        d = fmaf(xr[r][1], ca.y, d);
        d = fmaf(xr[r][2], ca.z, d);
        d = fmaf(xr[r][3], ca.w, d);
        d = fmaf(xr[r][4], cb.x, d);
        d = fmaf(xr[r][5], cb.y, d);
        d = fmaf(xr[r][6], cb.z, d);
        d = fmaf(xr[r][7], cb.w, d);
        // np: fl(-2*dot) is exact, then one rounded add of c2.
        const float s = fmaf(-2.0f, d, cc2);
        const bool lt = s < m1[r];             // strict <: first-min, matches np.argmin
        m1[r] = lt ? s : m1[r];
        i1[r] = lt ? c : i1[r];
      }
    }

#pragma unroll
    for (int r = 0; r < RPL; ++r) {
      const float4 wa = *reinterpret_cast<const float4*>(cB + i1[r] * BD);
      const float4 wb = *reinterpret_cast<const float4*>(cB + i1[r] * BD + 4);
      float* on = out + (size_t)(n0 + r * 64 + lane) * D;
      on[pc[0]] = wa.x;
      on[pc[1]] = wa.y;
      on[pc[2]] = wa.z;
      on[pc[3]] = wa.w;
      on[pc[4]] = wb.x;
      on[pc[5]] = wb.y;
      on[pc[6]] = wb.z;
      on[pc[7]] = wb.w;
    }
  }
}

extern "C" void kernel_launch(void* const* d_in, const int* in_sizes, int n_in,
                              void* d_out, int out_size, void* d_ws, size_t ws_size,
                              hipStream_t stream) {
  const float* x    = (const float*)d_in[0];
  const float* cent = (const float*)d_in[1];
  const int*   perm = (const int*)d_in[2];
  float*       out  = (float*)d_out;

  const size_t lds_bytes = (size_t)(NB * NC * BD + NB * NC) * sizeof(float); // 147456
  (void)hipFuncSetAttribute(reinterpret_cast<const void*>(&vq_np_exact),
                            hipFuncAttributeMaxDynamicSharedMemorySize,
                            (int)lds_bytes);

  dim3 grid(256);
  dim3 block(TPB);
  vq_np_exact<<<grid, block, lds_bytes, stream>>>(x, cent, perm, out);
}

// Round 13
// 483.622 us; speedup vs baseline: 1.2945x; 1.2945x over previous
//
#include <hip/hip_runtime.h>

// profileperm VQ encode+decode, bit-exact vs fp32-numpy reference (round-6 math kept
// verbatim: sgemm-style K=8 FMA chain, fmaf(-2,dot,c2), pairwise-tree c2, strict-< argmin).
//
// Round-6 counters: 1.5 GB HBM (scatter gather/write amplification) + 30% occupancy
// (147 KB codebook LDS -> 1 WG/CU). This version inverts the LDS usage:
//  - codebook via wave-uniform loads (readfirstlane base -> s_load) + per-wave
//    VGPR-distributed c2 (v_readlane), freeing all LDS
//  - LDS stages 128-row tiles: coalesced in, permuted gather from LDS, winners
//    written back in place, coalesced out  => ~256 MB total HBM, all float4.
//  - 66 KB LDS -> 2 WG/CU -> 8 waves/SIMD (vs 4), hiding codebook-load latency.

constexpr int N_ROWS = 262144;
constexpr int D   = 128;
constexpr int NB  = 16;   // blocks (== waves per workgroup)
constexpr int NC  = 256;  // centroids per block
constexpr int BD  = 8;    // block dim
constexpr int TPB = 1024; // 16 waves
constexpr int R   = 128;  // rows per chunk
constexpr int PS  = 132;  // padded LDS row stride (floats); 528 B, 16B-aligned
constexpr int GRID_X = 512;              // 2 workgroups per CU
constexpr int CHUNKS = N_ROWS / R;       // 2048 (divides exactly; 4 chunks/WG)

__global__ __launch_bounds__(TPB, 8)
void vq_fused(const float* __restrict__ x,
              const float* __restrict__ cent,
              const int*   __restrict__ perm,
              float*       __restrict__ out) {
  extern __shared__ float xs[];   // [R][PS]
  const int t    = threadIdx.x;
  const int wave = t >> 6;
  const int lane = t & 63;

  int pc[BD];  // permuted columns for this wave's block (wave-uniform values)
#pragma unroll
  for (int j = 0; j < BD; ++j) pc[j] = perm[wave * BD + j];

  // Compiler-visible uniform codebook base -> scalar loads in the hot loop.
  const int rb = __builtin_amdgcn_readfirstlane(wave);
  const float* cbase = cent + (size_t)rb * (NC * BD);

  // Per-wave distributed c2 (numpy pairwise tree, bit-exact): lane holds c = k*64+lane.
  float c2v[4];
#pragma unroll
  for (int k = 0; k < 4; ++k) {
    const float* c = cbase + (size_t)(k * 64 + lane) * BD;
    const float q0 = __fmul_rn(c[0], c[0]);
    const float q1 = __fmul_rn(c[1], c[1]);
    const float q2 = __fmul_rn(c[2], c[2]);
    const float q3 = __fmul_rn(c[3], c[3]);
    const float q4 = __fmul_rn(c[4], c[4]);
    const float q5 = __fmul_rn(c[5], c[5]);
    const float q6 = __fmul_rn(c[6], c[6]);
    const float q7 = __fmul_rn(c[7], c[7]);
    c2v[k] = __fadd_rn(__fadd_rn(__fadd_rn(q0, q1), __fadd_rn(q2, q3)),
                       __fadd_rn(__fadd_rn(q4, q5), __fadd_rn(q6, q7)));
  }

  for (int chunk = blockIdx.x; chunk < CHUNKS; chunk += GRID_X) {
    const size_t base = (size_t)chunk * R * D;

    // ---- stage in: 128 rows x 128 cols, fully coalesced float4 ----
#pragma unroll
    for (int k = 0; k < 4; ++k) {
      const int f   = t + k * TPB;        // float4 index 0..4095
      const int row = f >> 5;
      const int col = (f & 31) << 2;
      const float4 v = *reinterpret_cast<const float4*>(x + base + (size_t)f * 4);
      *reinterpret_cast<float4*>(&xs[row * PS + col]) = v;
    }
    __syncthreads();

    // ---- gather this wave's 8 permuted cols for 2 rows/lane ----
    float xr[2][BD];
#pragma unroll
    for (int rr = 0; rr < 2; ++rr) {
      const int lr = lane + rr * 64;
#pragma unroll
      for (int j = 0; j < BD; ++j) xr[rr][j] = xs[lr * PS + pc[j]];
    }
    __syncthreads();   // all waves done reading before in-place overwrite

    float m1[2] = {__builtin_inff(), __builtin_inff()};
    int   i1[2] = {0, 0};

#pragma unroll
    for (int k = 0; k < 4; ++k) {
#pragma unroll 4
      for (int cc = 0; cc < 64; ++cc) {
        const int c = k * 64 + cc;
        const float* cp = cbase + c * BD;   // uniform address -> s_load_dwordx8
        const float c0 = cp[0], c1 = cp[1], c2_ = cp[2], c3 = cp[3];
        const float c4 = cp[4], c5 = cp[5], c6 = cp[6], c7 = cp[7];
        const float csq = __uint_as_float(
            __builtin_amdgcn_readlane(__float_as_uint(c2v[k]), cc));
#pragma unroll
        for (int rr = 0; rr < 2; ++rr) {
          float d = __fmul_rn(xr[rr][0], c0);   // fl(x0*c0), then sgemm FMA chain
          d = fmaf(xr[rr][1], c1, d);
          d = fmaf(xr[rr][2], c2_, d);
          d = fmaf(xr[rr][3], c3, d);
          d = fmaf(xr[rr][4], c4, d);
          d = fmaf(xr[rr][5], c5, d);
          d = fmaf(xr[rr][6], c6, d);
          d = fmaf(xr[rr][7], c7, d);
          const float s = fmaf(-2.0f, d, csq);  // fl(-2*dot) exact, one rounded add
          const bool lt = s < m1[rr];           // strict <: first-min == np.argmin
          m1[rr] = lt ? s : m1[rr];
          i1[rr] = lt ? c : i1[rr];
        }
      }
    }

    // ---- winners -> LDS tile (in place), bit-exact centroid pass-through ----
#pragma unroll
    for (int rr = 0; rr < 2; ++rr) {
      const int lr = lane + rr * 64;
      const float4 wa = *reinterpret_cast<const float4*>(cbase + (size_t)i1[rr] * BD);
      const float4 wb = *reinterpret_cast<const float4*>(cbase + (size_t)i1[rr] * BD + 4);
      float* o = &xs[lr * PS];
      o[pc[0]] = wa.x; o[pc[1]] = wa.y; o[pc[2]] = wa.z; o[pc[3]] = wa.w;
      o[pc[4]] = wb.x; o[pc[5]] = wb.y; o[pc[6]] = wb.z; o[pc[7]] = wb.w;
    }
    __syncthreads();

    // ---- stage out: fully coalesced float4 ----
#pragma unroll
    for (int k = 0; k < 4; ++k) {
      const int f   = t + k * TPB;
      const int row = f >> 5;
      const int col = (f & 31) << 2;
      const float4 v = *reinterpret_cast<const float4*>(&xs[row * PS + col]);
      *reinterpret_cast<float4*>(out + base + (size_t)f * 4) = v;
    }
    __syncthreads();   // protect next chunk's stage-in
  }
}

extern "C" void kernel_launch(void* const* d_in, const int* in_sizes, int n_in,
                              void* d_out, int out_size, void* d_ws, size_t ws_size,
                              hipStream_t stream) {
  const float* x    = (const float*)d_in[0];
  const float* cent = (const float*)d_in[1];
  const int*   perm = (const int*)d_in[2];
  float*       out  = (float*)d_out;

  const size_t lds_bytes = (size_t)R * PS * sizeof(float); // 67584
  (void)hipFuncSetAttribute(reinterpret_cast<const void*>(&vq_fused),
                            hipFuncAttributeMaxDynamicSharedMemorySize,
                            (int)lds_bytes);

  vq_fused<<<dim3(GRID_X), dim3(TPB), lds_bytes, stream>>>(x, cent, perm, out);
}